// Round 13
// baseline (90.953 us; speedup 1.0000x reference)
//
#include <hip/hip_runtime.h>

#define DD 128

typedef __attribute__((ext_vector_type(8))) short bf16x8;
typedef __attribute__((ext_vector_type(4))) float f32x4;

__device__ __forceinline__ unsigned int cvt_pk_bf16(float lo, float hi) {
  unsigned int r;
  asm("v_cvt_pk_bf16_f32 %0, %1, %2" : "=v"(r) : "v"(lo), "v"(hi));
  return r;
}
__device__ __forceinline__ float bf_lo(unsigned int v) { return __uint_as_float(v << 16); }
__device__ __forceinline__ float bf_hi(unsigned int v) { return __uint_as_float(v & 0xFFFF0000u); }

// ---------------------------------------------------------------------------
// prep (r10 structure), block-partitioned jobs:
//  A (16 rows/block): xq = biased-int8(x), per-row scale sx[n]=max|x[n,:]|/127
//  B: CSR row offsets from sorted dst
//  C: B = [ W[j][k] ; KG^T[j][k] ] as bf16
// ---------------------------------------------------------------------------
__global__ __launch_bounds__(256) void prep_kernel(
    const float* __restrict__ x, const int* __restrict__ dst,
    const float* __restrict__ W, const float* __restrict__ KG,
    unsigned char* __restrict__ xq, float* __restrict__ sx,
    int* __restrict__ row_start, unsigned short* __restrict__ B,
    int N, int E, int ABLK, int BBLK) {
  int blk = blockIdx.x;
  int t = threadIdx.x;
  if (blk < ABLK) {
    int n = blk * 16 + (t >> 4);
    int lr = t & 15;
    if (n < N) {
      const float4* xr = (const float4*)(x + (size_t)n * DD);
      float4 va = xr[lr * 2], vb = xr[lr * 2 + 1];
      float m = fmaxf(fmaxf(fmaxf(fabsf(va.x), fabsf(va.y)), fmaxf(fabsf(va.z), fabsf(va.w))),
                      fmaxf(fmaxf(fabsf(vb.x), fabsf(vb.y)), fmaxf(fabsf(vb.z), fabsf(vb.w))));
#pragma unroll
      for (int d = 1; d < 16; d <<= 1) m = fmaxf(m, __shfl_xor(m, d, 16));
      m = fmaxf(m, 1e-20f);
      float inv = 127.0f / m;
      unsigned int q0 = (unsigned int)(__float2int_rn(va.x * inv) + 128);
      unsigned int q1 = (unsigned int)(__float2int_rn(va.y * inv) + 128);
      unsigned int q2 = (unsigned int)(__float2int_rn(va.z * inv) + 128);
      unsigned int q3 = (unsigned int)(__float2int_rn(va.w * inv) + 128);
      unsigned int q4 = (unsigned int)(__float2int_rn(vb.x * inv) + 128);
      unsigned int q5 = (unsigned int)(__float2int_rn(vb.y * inv) + 128);
      unsigned int q6 = (unsigned int)(__float2int_rn(vb.z * inv) + 128);
      unsigned int q7 = (unsigned int)(__float2int_rn(vb.w * inv) + 128);
      uint2 qp;
      qp.x = q0 | (q1 << 8) | (q2 << 16) | (q3 << 24);
      qp.y = q4 | (q5 << 8) | (q6 << 16) | (q7 << 24);
      ((uint2*)xq)[(size_t)n * 16 + lr] = qp;
      if (lr == 0) sx[n] = m * (1.0f / 127.0f);
    }
  } else if (blk < ABLK + BBLK) {
    int e = (blk - ABLK) * 256 + t;
    if (e <= E) {
      if (e == 0) {
        int d0 = dst[0];
        for (int n = 0; n <= d0; ++n) row_start[n] = 0;
      } else if (e == E) {
        for (int n = dst[E - 1] + 1; n <= N; ++n) row_start[n] = E;
      } else {
        int d = dst[e], dp = dst[e - 1];
        for (int n = dp + 1; n <= d; ++n) row_start[n] = e;
      }
    }
  } else {
    int e2 = (blk - ABLK - BBLK) * 256 + t;
    if (e2 < 2 * DD * DD) {
      int j = e2 >> 7, k = e2 & 127;
      float v = (j < DD) ? W[j * DD + k] : KG[k * DD + (j - DD)];
      B[e2] = (unsigned short)cvt_pk_bf16(v, v);
    }
  }
}

// ---------------------------------------------------------------------------
// agg_gemm: per 16-node block (4 waves):
//   phase 0: stage x tile from xq (threads 0-127) -> bf16 LDS [16][128], swz
//   phase 1: gather-aggregate (r10 geometry: 4 nodes/wave, 16 lanes/node,
//            int8 rows, 4-edge clamped unroll) -> agg row held in registers
//   phase 2: agg tile -> LDS (4KB, swz); sync;
//            S = relu(agg @ W^T + sumw*b); G = sigmoid(x @ KG + bg);
//            out = G*S + (1-G)*x   (one 16-node MFMA tile, 8 j-tiles)
// Deletes the aggb global write+read (51MB) and the third launch.
// ---------------------------------------------------------------------------
__global__ __launch_bounds__(256, 6) void agg_gemm(
    const unsigned char* __restrict__ xq, const float* __restrict__ sx,
    const int* __restrict__ src, const float* __restrict__ ew,
    const int* __restrict__ row_start, const unsigned short* __restrict__ B,
    const float* __restrict__ bias, const float* __restrict__ bg,
    float* __restrict__ out, int N, int E) {
  __shared__ char smem[8320];
  unsigned short* sX = (unsigned short*)smem;           // [16][128] bf16, swz
  unsigned short* sA = (unsigned short*)(smem + 4096);  // [16][128] bf16, swz
  float* sumw_s = (float*)(smem + 8192);                // 16 f32
  int t = threadIdx.x;
  int wid = t >> 6, lane = t & 63;
  int g = lane >> 4, lr = lane & 15, lk2 = lane >> 4;
  int M0 = blockIdx.x * 16;

  // ---- phase 0: stage x tile (128 threads, one uint4 of 16 int8 each)
  if (t < 128) {
    int r = t >> 3, c = t & 7;
    int n = M0 + r;
    uint4 v;
    float s;
    if (n < N) {
      v = ((const uint4*)(xq + (size_t)n * DD))[c];
      s = sx[n];
    } else {
      v = make_uint4(0, 0, 0, 0);
      s = 0.f;
    }
    float nb = -128.0f * s;
    unsigned int w[4] = {v.x, v.y, v.z, v.w};
    unsigned int o[8];
#pragma unroll
    for (int q = 0; q < 4; ++q) {
      float e0 = fmaf(s, (float)(w[q] & 0xFF), nb);
      float e1 = fmaf(s, (float)((w[q] >> 8) & 0xFF), nb);
      float e2 = fmaf(s, (float)((w[q] >> 16) & 0xFF), nb);
      float e3 = fmaf(s, (float)(w[q] >> 24), nb);
      o[q * 2]     = cvt_pk_bf16(e0, e1);
      o[q * 2 + 1] = cvt_pk_bf16(e2, e3);
    }
    int base = r * 256 + c * 32;
    uint4 lo = {o[0], o[1], o[2], o[3]};
    uint4 hi = {o[4], o[5], o[6], o[7]};
    *(uint4*)((char*)sX + ((base) ^ ((r & 7) << 4)))      = lo;
    *(uint4*)((char*)sX + ((base + 16) ^ ((r & 7) << 4))) = hi;
  }

  // ---- phase 1: gather-aggregate (node n = M0 + wid*4 + g)
  int n = M0 + wid * 4 + g;
  bool valid = (n < N);
  int b = valid ? row_start[n] : 0;
  int cnt = valid ? (row_start[n + 1] - b) : 0;
  const uint2* x8 = (const uint2*)xq;

  float a[8];
#pragma unroll
  for (int k = 0; k < 8; ++k) a[k] = 0.f;
  float wsum = 0.f, wsc = 0.f;
  int clampj = cnt > 0 ? cnt - 1 : 0;

  int i = 0;
  while (__any(i < cnt)) {
#pragma unroll
    for (int u = 0; u < 4; ++u) {
      int ii = i + u;
      int jj = ii < clampj ? ii : clampj;
      int j = b + jj;
      if (j > E - 1) j = E - 1;
      float wt = (ii < cnt) ? ew[j] : 0.f;
      int s = src[j];
      float ws = wt * sx[s];
      uint2 v = x8[(size_t)s * 16 + lr];
      wsum += wt;
      wsc += ws;
      a[0] += ws * (float)(v.x & 0xFF);
      a[1] += ws * (float)((v.x >> 8) & 0xFF);
      a[2] += ws * (float)((v.x >> 16) & 0xFF);
      a[3] += ws * (float)(v.x >> 24);
      a[4] += ws * (float)(v.y & 0xFF);
      a[5] += ws * (float)((v.y >> 8) & 0xFF);
      a[6] += ws * (float)((v.y >> 16) & 0xFF);
      a[7] += ws * (float)(v.y >> 24);
    }
    i += 4;
  }
  float c0 = 128.0f * wsc;
#pragma unroll
  for (int k = 0; k < 8; ++k) a[k] -= c0;

  // ---- agg row -> LDS (row rt, 16B per lane, swizzled)
  {
    int rt = wid * 4 + g;
    uint4 o;
    o.x = cvt_pk_bf16(a[0], a[1]);
    o.y = cvt_pk_bf16(a[2], a[3]);
    o.z = cvt_pk_bf16(a[4], a[5]);
    o.w = cvt_pk_bf16(a[6], a[7]);
    *(uint4*)((char*)sA + ((rt * 256 + lr * 16) ^ ((rt & 7) << 4))) = o;
    if (lr == 0) sumw_s[rt] = wsum;
  }
  __syncthreads();

  // ---- phase 2: dual MFMA (one 16-node tile; wave wid owns j-tiles wid*2,+1)
  f32x4 accS[2], accG[2];
#pragma unroll
  for (int m = 0; m < 2; ++m) {
    accS[m] = (f32x4){0.f, 0.f, 0.f, 0.f};
    accG[m] = (f32x4){0.f, 0.f, 0.f, 0.f};
  }

#pragma unroll
  for (int kc = 0; kc < 4; ++kc) {
    int kb = (kc * 32 + lk2 * 8) * 2;
    bf16x8 wSk[2], wGk[2];
#pragma unroll
    for (int m = 0; m < 2; ++m) {
      int j = (wid * 2 + m) * 16 + lr;
      wSk[m] = *(const bf16x8*)(B + (size_t)j * DD + kc * 32 + lk2 * 8);
      wGk[m] = *(const bf16x8*)(B + (size_t)(DD + j) * DD + kc * 32 + lk2 * 8);
    }
    bf16x8 af = *(const bf16x8*)((const char*)sA + ((lr * 256 + kb) ^ ((lr & 7) << 4)));
    bf16x8 xf = *(const bf16x8*)((const char*)sX + ((lr * 256 + kb) ^ ((lr & 7) << 4)));
#pragma unroll
    for (int m = 0; m < 2; ++m) {
      accS[m] = __builtin_amdgcn_mfma_f32_16x16x32_bf16(wSk[m], af, accS[m], 0, 0, 0);
      accG[m] = __builtin_amdgcn_mfma_f32_16x16x32_bf16(wGk[m], xf, accG[m], 0, 0, 0);
    }
  }

  // ---- epilogue: j0 = (wid*2+m)*16 + lk2*4; node = M0 + lr
  int node = M0 + lr;
  if (node < N) {
    float sw = sumw_s[lr];
#pragma unroll
    for (int m = 0; m < 2; ++m) {
      int j0 = (wid * 2 + m) * 16 + lk2 * 4;
      float4 b4 = *(const float4*)&bias[j0];
      float4 bg4 = *(const float4*)&bg[j0];
      float ba[4] = {b4.x, b4.y, b4.z, b4.w};
      float bga[4] = {bg4.x, bg4.y, bg4.z, bg4.w};
      uint2 qx = *(const uint2*)((const char*)sX + ((lr * 256 + j0 * 2) ^ ((lr & 7) << 4)));
      float xr[4] = {bf_lo(qx.x), bf_hi(qx.x), bf_lo(qx.y), bf_hi(qx.y)};
      f32x4 vs = accS[m], vg = accG[m];
      float4 o;
      float* op = &o.x;
#pragma unroll
      for (int reg = 0; reg < 4; ++reg) {
        float s = fmaxf(vs[reg] + sw * ba[reg], 0.f);
        float gt = 1.0f / (1.0f + __expf(-(vg[reg] + bga[reg])));
        op[reg] = gt * s + (1.0f - gt) * xr[reg];
      }
      *(float4*)&out[(size_t)node * DD + j0] = o;
    }
  }
}

// ---------------------------------------------------------------------------
extern "C" void kernel_launch(void* const* d_in, const int* in_sizes, int n_in,
                              void* d_out, int out_size, void* d_ws, size_t ws_size,
                              hipStream_t stream) {
  const float* x   = (const float*)d_in[0];
  const int*   src = (const int*)d_in[1];
  const int*   dst = (const int*)d_in[2];
  const float* ew  = (const float*)d_in[3];
  const float* W   = (const float*)d_in[4];
  const float* b   = (const float*)d_in[5];
  const float* KG  = (const float*)d_in[6];
  const float* bg  = (const float*)d_in[7];
  float* out = (float*)d_out;

  int N = in_sizes[0] / DD;
  int E = in_sizes[1];

  unsigned char* xq = (unsigned char*)d_ws;                // N*128 u8
  float* sx = (float*)(xq + (size_t)N * DD);               // N f32
  unsigned short* B = (unsigned short*)(sx + N);           // 2*128*128 bf16
  int* row_start = (int*)(B + 2 * DD * DD);                // N+1 ints

  int ABLK = (N + 15) / 16;
  int BBLK = (E + 1 + 255) / 256;
  int CBLK = (2 * DD * DD + 255) / 256;
  prep_kernel<<<ABLK + BBLK + CBLK, 256, 0, stream>>>(x, dst, W, KG, xq, sx,
                                                      row_start, B, N, E, ABLK, BBLK);
  agg_gemm<<<(N + 15) / 16, 256, 0, stream>>>(xq, sx, src, ew, row_start, B, b, bg, out, N, E);
}

// Round 15
// 73.228 us; speedup vs baseline: 1.2421x; 1.2421x over previous
//
#include <hip/hip_runtime.h>

#define DD 128

typedef __attribute__((ext_vector_type(8))) short bf16x8;
typedef __attribute__((ext_vector_type(4))) float f32x4;

__device__ __forceinline__ unsigned int cvt_pk_bf16(float lo, float hi) {
  unsigned int r;
  asm("v_cvt_pk_bf16_f32 %0, %1, %2" : "=v"(r) : "v"(lo), "v"(hi));
  return r;
}
__device__ __forceinline__ float bf_lo(unsigned int v) { return __uint_as_float(v << 16); }
__device__ __forceinline__ float bf_hi(unsigned int v) { return __uint_as_float(v & 0xFFFF0000u); }

// ---------------------------------------------------------------------------
// prep (r10 exact), block-partitioned jobs:
//  A (16 rows/block): xq = biased-int8(x), per-row scale sx[n]=max|x[n,:]|/127
//  B: CSR row offsets from sorted dst
//  C: B = [ W[j][k] ; KG^T[j][k] ] as bf16
// ---------------------------------------------------------------------------
__global__ __launch_bounds__(256) void prep_kernel(
    const float* __restrict__ x, const int* __restrict__ dst,
    const float* __restrict__ W, const float* __restrict__ KG,
    unsigned char* __restrict__ xq, float* __restrict__ sx,
    int* __restrict__ row_start, unsigned short* __restrict__ B,
    int N, int E, int ABLK, int BBLK) {
  int blk = blockIdx.x;
  int t = threadIdx.x;
  if (blk < ABLK) {
    int n = blk * 16 + (t >> 4);
    int lr = t & 15;
    if (n < N) {
      const float4* xr = (const float4*)(x + (size_t)n * DD);
      float4 va = xr[lr * 2], vb = xr[lr * 2 + 1];
      float m = fmaxf(fmaxf(fmaxf(fabsf(va.x), fabsf(va.y)), fmaxf(fabsf(va.z), fabsf(va.w))),
                      fmaxf(fmaxf(fabsf(vb.x), fabsf(vb.y)), fmaxf(fabsf(vb.z), fabsf(vb.w))));
#pragma unroll
      for (int d = 1; d < 16; d <<= 1) m = fmaxf(m, __shfl_xor(m, d, 16));
      m = fmaxf(m, 1e-20f);
      float inv = 127.0f / m;
      unsigned int q0 = (unsigned int)(__float2int_rn(va.x * inv) + 128);
      unsigned int q1 = (unsigned int)(__float2int_rn(va.y * inv) + 128);
      unsigned int q2 = (unsigned int)(__float2int_rn(va.z * inv) + 128);
      unsigned int q3 = (unsigned int)(__float2int_rn(va.w * inv) + 128);
      unsigned int q4 = (unsigned int)(__float2int_rn(vb.x * inv) + 128);
      unsigned int q5 = (unsigned int)(__float2int_rn(vb.y * inv) + 128);
      unsigned int q6 = (unsigned int)(__float2int_rn(vb.z * inv) + 128);
      unsigned int q7 = (unsigned int)(__float2int_rn(vb.w * inv) + 128);
      uint2 qp;
      qp.x = q0 | (q1 << 8) | (q2 << 16) | (q3 << 24);
      qp.y = q4 | (q5 << 8) | (q6 << 16) | (q7 << 24);
      ((uint2*)xq)[(size_t)n * 16 + lr] = qp;
      if (lr == 0) sx[n] = m * (1.0f / 127.0f);
    }
  } else if (blk < ABLK + BBLK) {
    int e = (blk - ABLK) * 256 + t;
    if (e <= E) {
      if (e == 0) {
        int d0 = dst[0];
        for (int n = 0; n <= d0; ++n) row_start[n] = 0;
      } else if (e == E) {
        for (int n = dst[E - 1] + 1; n <= N; ++n) row_start[n] = E;
      } else {
        int d = dst[e], dp = dst[e - 1];
        for (int n = dp + 1; n <= d; ++n) row_start[n] = e;
      }
    }
  } else {
    int e2 = (blk - ABLK - BBLK) * 256 + t;
    if (e2 < 2 * DD * DD) {
      int j = e2 >> 7, k = e2 & 127;
      float v = (j < DD) ? W[j * DD + k] : KG[k * DD + (j - DD)];
      B[e2] = (unsigned short)cvt_pk_bf16(v, v);
    }
  }
}

// ---------------------------------------------------------------------------
// scatter_agg (r10 exact): agg[n] = sum ew_e * x[src_e] via int8 table,
//   x ~ s*(u8-128);  sumw[n] = sum ew_e.
// 4 nodes/wave (16 lanes each, uint2 = 8B/lane -> 128B row); 4-edge unroll.
// ---------------------------------------------------------------------------
__global__ __launch_bounds__(256, 8) void scatter_agg(
    const unsigned char* __restrict__ xq, const float* __restrict__ sx,
    const int* __restrict__ src, const float* __restrict__ ew,
    const int* __restrict__ row_start, unsigned short* __restrict__ aggb,
    float* __restrict__ sumw, int N, int E) {
  int t = threadIdx.x;
  int wid = t >> 6, lane = t & 63;
  int g = lane >> 4, lr = lane & 15;
  int n = blockIdx.x * 16 + wid * 4 + g;
  bool valid = (n < N);
  int b = valid ? row_start[n] : 0;
  int cnt = valid ? (row_start[n + 1] - b) : 0;
  const uint2* x8 = (const uint2*)xq;

  float a[8];
#pragma unroll
  for (int k = 0; k < 8; ++k) a[k] = 0.f;
  float wsum = 0.f, wsc = 0.f;
  int clampj = cnt > 0 ? cnt - 1 : 0;

  int i = 0;
  while (__any(i < cnt)) {
#pragma unroll
    for (int u = 0; u < 4; ++u) {
      int ii = i + u;
      int jj = ii < clampj ? ii : clampj;
      int j = b + jj;
      if (j > E - 1) j = E - 1;
      float wt = (ii < cnt) ? ew[j] : 0.f;
      int s = src[j];
      float ws = wt * sx[s];
      uint2 v = x8[(size_t)s * 16 + lr];
      wsum += wt;
      wsc += ws;
      a[0] += ws * (float)(v.x & 0xFF);
      a[1] += ws * (float)((v.x >> 8) & 0xFF);
      a[2] += ws * (float)((v.x >> 16) & 0xFF);
      a[3] += ws * (float)(v.x >> 24);
      a[4] += ws * (float)(v.y & 0xFF);
      a[5] += ws * (float)((v.y >> 8) & 0xFF);
      a[6] += ws * (float)((v.y >> 16) & 0xFF);
      a[7] += ws * (float)(v.y >> 24);
    }
    i += 4;
  }
  float c = 128.0f * wsc;
#pragma unroll
  for (int k = 0; k < 8; ++k) a[k] -= c;

  if (valid) {
    uint4 o;
    o.x = cvt_pk_bf16(a[0], a[1]);
    o.y = cvt_pk_bf16(a[2], a[3]);
    o.z = cvt_pk_bf16(a[4], a[5]);
    o.w = cvt_pk_bf16(a[6], a[7]);
    ((uint4*)aggb)[(size_t)n * 16 + lr] = o;
    if (lr == 0) sumw[n] = wsum;
  }
}

// ---------------------------------------------------------------------------
// fused_gemm v5b: per 64-node tile:
//   S = relu(aggb @ W^T + sumw*b);  G = sigmoid(x @ KG + bg);
//   out = G*S + (1-G)*x
// vs v5: epilogue nr-outer/m-inner (64B store pairs merge to 128B lines),
// non-temporal out stores (f32x4 ext-vector), hoisted sumw/bias.
// ---------------------------------------------------------------------------
__global__ __launch_bounds__(256, 3) void fused_gemm(
    const unsigned char* __restrict__ xq, const float* __restrict__ sx,
    const unsigned short* __restrict__ aggb, const unsigned short* __restrict__ B,
    const float* __restrict__ sumw, const float* __restrict__ bias,
    const float* __restrict__ bg, float* __restrict__ out, int N) {
  __shared__ char smem[32 * 1024];
  unsigned short* sX = (unsigned short*)smem;            // 16KB: x tile bf16 (swz)
  unsigned short* sA = (unsigned short*)(smem + 16384);  // 16KB: agg tile (swz)
  int t = threadIdx.x;
  int wid = t >> 6, lane = t & 63;
  int lr = lane & 15, lk2 = lane >> 4;
  int jw = wid * 32;
  int M0 = blockIdx.x * 64;

  // ---- persistent weight fragments: W rows (support) and KG^T rows (gate)
  bf16x8 wS[4][2], wG[4][2];  // [kc][m]
#pragma unroll
  for (int kc = 0; kc < 4; ++kc)
#pragma unroll
    for (int m = 0; m < 2; ++m) {
      int j = jw + m * 16 + lr;
      wS[kc][m] = *(const bf16x8*)(B + (size_t)j * DD + kc * 32 + lk2 * 8);
      wG[kc][m] = *(const bf16x8*)(B + (size_t)(DD + j) * DD + kc * 32 + lk2 * 8);
    }

  // ---- stage x tile from xq: 512 uint4 (16 int8 each), dequant -> bf16, swz
#pragma unroll
  for (int i = 0; i < 2; ++i) {
    int idx = i * 256 + t;
    int r = idx >> 3;           // row in tile (8 uint4 per 128B row)
    int c = idx & 7;            // 16-byte chunk
    uint4 v;
    float s;
    if (M0 + r < N) {
      v = ((const uint4*)(xq + (size_t)(M0 + r) * DD))[c];
      s = sx[M0 + r];
    } else {
      v = make_uint4(0, 0, 0, 0);
      s = 0.f;
    }
    float nb = -128.0f * s;
    unsigned int w[4] = {v.x, v.y, v.z, v.w};
    unsigned int o[8];
#pragma unroll
    for (int q = 0; q < 4; ++q) {
      float e0 = fmaf(s, (float)(w[q] & 0xFF), nb);
      float e1 = fmaf(s, (float)((w[q] >> 8) & 0xFF), nb);
      float e2 = fmaf(s, (float)((w[q] >> 16) & 0xFF), nb);
      float e3 = fmaf(s, (float)(w[q] >> 24), nb);
      o[q * 2]     = cvt_pk_bf16(e0, e1);
      o[q * 2 + 1] = cvt_pk_bf16(e2, e3);
    }
    int base = r * 256 + c * 32;
    uint4 lo = {o[0], o[1], o[2], o[3]};
    uint4 hi = {o[4], o[5], o[6], o[7]};
    *(uint4*)((char*)sX + ((base) ^ ((r & 7) << 4)))      = lo;
    *(uint4*)((char*)sX + ((base + 16) ^ ((r & 7) << 4))) = hi;
  }
  // ---- stage agg tile (1024 uint4, swizzled)
#pragma unroll
  for (int i = 0; i < 4; ++i) {
    int idx = i * 256 + t;
    int r = idx >> 4, c = idx & 15;
    uint4 va;
    if (M0 + r < N) va = ((const uint4*)(aggb + (size_t)(M0 + r) * DD))[c];
    else            va = make_uint4(0, 0, 0, 0);
    int off = (r * 256 + c * 16) ^ ((r & 7) << 4);
    *(uint4*)((char*)sA + off) = va;
  }
  __syncthreads();

  f32x4 accS[2][4], accG[2][4];
#pragma unroll
  for (int m = 0; m < 2; ++m)
#pragma unroll
    for (int nr = 0; nr < 4; ++nr) {
      accS[m][nr] = (f32x4){0.f, 0.f, 0.f, 0.f};
      accG[m][nr] = (f32x4){0.f, 0.f, 0.f, 0.f};
    }

#pragma unroll
  for (int kc = 0; kc < 4; ++kc) {
    int kb = (kc * 32 + lk2 * 8) * 2;
    bf16x8 af[4], xf[4];
#pragma unroll
    for (int nr = 0; nr < 4; ++nr) {
      int r = nr * 16 + lr;
      int off = (r * 256 + kb) ^ ((r & 7) << 4);
      af[nr] = *(const bf16x8*)((const char*)sA + off);
      xf[nr] = *(const bf16x8*)((const char*)sX + off);
    }
#pragma unroll
    for (int m = 0; m < 2; ++m)
#pragma unroll
      for (int nr = 0; nr < 4; ++nr) {
        accS[m][nr] = __builtin_amdgcn_mfma_f32_16x16x32_bf16(wS[kc][m], af[nr], accS[m][nr], 0, 0, 0);
        accG[m][nr] = __builtin_amdgcn_mfma_f32_16x16x32_bf16(wG[kc][m], xf[nr], accG[m][nr], 0, 0, 0);
      }
  }

  // ---- epilogue: nr outer, m inner -> the two 64B half-row stores pair up.
  float ba[2][4], bga[2][4];
#pragma unroll
  for (int m = 0; m < 2; ++m) {
    int j0 = jw + m * 16 + lk2 * 4;
    *(float4*)ba[m]  = *(const float4*)&bias[j0];
    *(float4*)bga[m] = *(const float4*)&bg[j0];
  }
#pragma unroll
  for (int nr = 0; nr < 4; ++nr) {
    int node = M0 + nr * 16 + lr;
    if (node < N) {
      float sw = sumw[node];
      int r = nr * 16 + lr;
#pragma unroll
      for (int m = 0; m < 2; ++m) {
        int j0 = jw + m * 16 + lk2 * 4;
        uint2 qx = *(const uint2*)((const char*)sX + ((r * 256 + j0 * 2) ^ ((r & 7) << 4)));
        float xr[4] = {bf_lo(qx.x), bf_hi(qx.x), bf_lo(qx.y), bf_hi(qx.y)};
        f32x4 vs = accS[m][nr], vg = accG[m][nr];
        f32x4 o;
#pragma unroll
        for (int reg = 0; reg < 4; ++reg) {
          float s = fmaxf(vs[reg] + sw * ba[m][reg], 0.f);
          float g = 1.0f / (1.0f + __expf(-(vg[reg] + bga[m][reg])));
          o[reg] = g * s + (1.0f - g) * xr[reg];
        }
        __builtin_nontemporal_store(o, (f32x4*)&out[(size_t)node * DD + j0]);
      }
    }
  }
}

// ---------------------------------------------------------------------------
extern "C" void kernel_launch(void* const* d_in, const int* in_sizes, int n_in,
                              void* d_out, int out_size, void* d_ws, size_t ws_size,
                              hipStream_t stream) {
  const float* x   = (const float*)d_in[0];
  const int*   src = (const int*)d_in[1];
  const int*   dst = (const int*)d_in[2];
  const float* ew  = (const float*)d_in[3];
  const float* W   = (const float*)d_in[4];
  const float* b   = (const float*)d_in[5];
  const float* KG  = (const float*)d_in[6];
  const float* bg  = (const float*)d_in[7];
  float* out = (float*)d_out;

  int N = in_sizes[0] / DD;
  int E = in_sizes[1];

  unsigned short* aggb = (unsigned short*)d_ws;            // N*128 bf16
  unsigned char* xq = (unsigned char*)(aggb + (size_t)N * DD);  // N*128 u8
  float* sx = (float*)(xq + (size_t)N * DD);               // N f32
  float* sumw = sx + N;                                    // N f32
  unsigned short* B = (unsigned short*)(sumw + N);         // 2*128*128 bf16
  int* row_start = (int*)(B + 2 * DD * DD);                // N+1 ints

  int ABLK = (N + 15) / 16;
  int BBLK = (E + 1 + 255) / 256;
  int CBLK = (2 * DD * DD + 255) / 256;
  prep_kernel<<<ABLK + BBLK + CBLK, 256, 0, stream>>>(x, dst, W, KG, xq, sx,
                                                      row_start, B, N, E, ABLK, BBLK);
  scatter_agg<<<(N + 15) / 16, 256, 0, stream>>>(xq, sx, src, ew, row_start, aggb, sumw, N, E);
  fused_gemm<<<(N + 63) / 64, 256, 0, stream>>>(xq, sx, aggb, B, sumw, b, bg, out, N);
}